// Round 4
// baseline (208.179 us; speedup 1.0000x reference)
//
#include <hip/hip_runtime.h>

// LIF layer fused step, f32.
// Inputs (setup_inputs order):
//   d_in[0] input_spikes [8192]      f32
//   d_in[1] voltages     [1, 8192]   f32
//   d_in[2] synapses     [8192,8192] f32
//   d_in[3] weights      [8192,8192] f32
// Outputs (return order, concatenated flat in d_out, f32):
//   [0 .. 8192)            spikes (bool -> 0.0/1.0)
//   [8192 .. 16384)        v_new
//   [16384 .. 16384+64M)   syn

#define V_DECAY 0.99004983374916811f   // exp(-1/100)
#define S_DECAY 0.98019867330675525f   // exp(-1/50)
#define THRESH  1.0f

constexpr int N_IN  = 8192;
constexpr int N_OUT = 8192;
constexpr int COLS_PER_BLOCK = 1024;               // 256 threads x 4 floats
constexpr int COL_TILES = N_OUT / COLS_PER_BLOCK;  // 8
constexpr int UNROLL = 4;                          // loads in flight: 2*UNROLL

typedef float f32x4 __attribute__((ext_vector_type(4)));

// Kernel 1: syn = synapses*S_DECAY + weights*spike_row; write syn; emit
// per-(row-chunk, column) partial sums into d_ws.
// Manual load/compute split per UNROLL group: all 2*UNROLL dwordx4 loads are
// issued back-to-back (static register indices) before any compute/store, so
// each wave keeps ~8 vector loads in flight. No NT stores (they serialize the
// vmcnt queue: next-iter load waits retire behind the HBM-deep store).
__global__ __launch_bounds__(256) void lif_syn_kernel(
    const float* __restrict__ input_spikes,
    const float* __restrict__ synapses,
    const float* __restrict__ weights,
    float* __restrict__ syn_out,
    float* __restrict__ partials,       // [rowChunks][N_OUT]
    int rowsPerChunk)
{
    const int ct   = blockIdx.x % COL_TILES;
    const int rc   = blockIdx.x / COL_TILES;
    const int col  = ct * COLS_PER_BLOCK + threadIdx.x * 4;
    const int row0 = rc * rowsPerChunk;

    f32x4 acc = (f32x4)(0.f);
    for (int r = 0; r < rowsPerChunk; r += UNROLL) {
        f32x4 s[UNROLL], w[UNROLL];
        float sp[UNROLL];
        #pragma unroll
        for (int u = 0; u < UNROLL; ++u) {
            const size_t idx = (size_t)(row0 + r + u) * N_OUT + col;
            s[u] = *reinterpret_cast<const f32x4*>(synapses + idx);
            w[u] = *reinterpret_cast<const f32x4*>(weights  + idx);
            sp[u] = input_spikes[row0 + r + u];   // block-uniform -> s_load
        }
        #pragma unroll
        for (int u = 0; u < UNROLL; ++u) {
            const size_t idx = (size_t)(row0 + r + u) * N_OUT + col;
            const f32x4 o = s[u] * S_DECAY + w[u] * sp[u];
            *reinterpret_cast<f32x4*>(syn_out + idx) = o;
            acc += o;
        }
    }
    *reinterpret_cast<f32x4*>(partials + (size_t)rc * N_OUT + col) = acc;
}

// Kernel 2: reduce partials per column, compute spike + v_new.
__global__ __launch_bounds__(256) void lif_v_kernel(
    const float* __restrict__ voltages,
    const float* __restrict__ partials,
    float* __restrict__ out,            // out[0..N_OUT)=spikes, [N_OUT..2N)=v_new
    int rowChunks)
{
    const int c = blockIdx.x * blockDim.x + threadIdx.x;
    const float v     = voltages[c] * V_DECAY;
    const float spike = (v >= THRESH) ? 1.0f : 0.0f;
    float sum = 0.f;
    #pragma unroll 4
    for (int rc = 0; rc < rowChunks; ++rc)
        sum += partials[(size_t)rc * N_OUT + c];   // coalesced across threads
    out[c]          = spike;
    out[N_OUT + c]  = v + sum - spike * THRESH;
}

extern "C" void kernel_launch(void* const* d_in, const int* in_sizes, int n_in,
                              void* d_out, int out_size, void* d_ws, size_t ws_size,
                              hipStream_t stream) {
    const float* input_spikes = (const float*)d_in[0];
    const float* voltages     = (const float*)d_in[1];
    const float* synapses     = (const float*)d_in[2];
    const float* weights      = (const float*)d_in[3];

    float* out      = (float*)d_out;
    float* syn_out  = out + 2 * N_OUT;
    float* partials = (float*)d_ws;

    // Largest power-of-two row-chunk count whose partial buffer fits d_ws.
    // 512 chunks -> 16 rows/block -> 4096 blocks.
    int rowChunks = 512;
    while (rowChunks > 1 &&
           (size_t)rowChunks * N_OUT * sizeof(float) > ws_size)
        rowChunks >>= 1;
    const int rowsPerChunk = N_IN / rowChunks;

    lif_syn_kernel<<<dim3(COL_TILES * rowChunks), dim3(256), 0, stream>>>(
        input_spikes, synapses, weights, syn_out, partials, rowsPerChunk);

    lif_v_kernel<<<dim3(N_OUT / 256), dim3(256), 0, stream>>>(
        voltages, partials, out, rowChunks);
}

// Round 6
// 167.587 us; speedup vs baseline: 1.2422x; 1.2422x over previous
//
#include <hip/hip_runtime.h>

// LIF layer fused step, f32.
// Inputs: input_spikes[8192], voltages[1,8192], synapses[8192,8192], weights[8192,8192]
// Outputs (concat in d_out): spikes[8192] (0/1 f32), v_new[8192], syn[8192,8192]

#define V_DECAY 0.99004983374916811f   // exp(-1/100)
#define S_DECAY 0.98019867330675525f   // exp(-1/50)
#define THRESH  1.0f

constexpr int N_IN  = 8192;
constexpr int N_OUT = 8192;
constexpr int STEPS = 8;   // 256 threads * 4 floats * 8 steps = 8192 cols/row

typedef float f32x4 __attribute__((ext_vector_type(4)));

// Kernel 1: each block owns `rowsPerBlock` fully CONTIGUOUS rows (3 streams walk
// linearly). Per row: issue all 16 dwordx4 loads, then sched_barrier(0) forces
// them all live (16 loads in flight per wave), then 8x { fma, store, acc }.
__global__ __launch_bounds__(256) void lif_syn_kernel(
    const float* __restrict__ input_spikes,
    const float* __restrict__ synapses,
    const float* __restrict__ weights,
    float* __restrict__ syn_out,
    float* __restrict__ partials,       // [gridDim.x][N_OUT]
    int rowsPerBlock)
{
    const int rc   = blockIdx.x;
    const int row0 = rc * rowsPerBlock;
    const int c0   = threadIdx.x * 4;

    f32x4 acc[STEPS];
    #pragma unroll
    for (int s = 0; s < STEPS; ++s) acc[s] = (f32x4)(0.f);

    for (int r = 0; r < rowsPerBlock; ++r) {
        const float  sp   = input_spikes[row0 + r];     // uniform -> s_load
        const size_t base = (size_t)(row0 + r) * N_OUT + c0;
        f32x4 sv[STEPS], wv[STEPS];
        #pragma unroll
        for (int s = 0; s < STEPS; ++s) {
            sv[s] = *reinterpret_cast<const f32x4*>(synapses + base + s * 1024);
            wv[s] = *reinterpret_cast<const f32x4*>(weights  + base + s * 1024);
        }
        __builtin_amdgcn_sched_barrier(0);  // keep all 16 loads in flight
        #pragma unroll
        for (int s = 0; s < STEPS; ++s) {
            const f32x4 o = sv[s] * S_DECAY + wv[s] * sp;
            *reinterpret_cast<f32x4*>(syn_out + base + s * 1024) = o;
            acc[s] += o;
        }
    }
    const size_t pbase = (size_t)rc * N_OUT + c0;
    #pragma unroll
    for (int s = 0; s < STEPS; ++s)
        *reinterpret_cast<f32x4*>(partials + pbase + s * 1024) = acc[s];
}

// Kernel 2a: 16:1 reduction. Group g reads rows [16g, 16g+16) and writes row
// 16g (its OWN first input row). Each cell is written only by the thread that
// read it — no cross-group read/write overlap, fully deterministic.
__global__ __launch_bounds__(256) void lif_reduce_kernel(
    float* __restrict__ partials)
{
    const int ctiles = N_OUT / 256;                    // 32
    const int c = (blockIdx.x % ctiles) * 256 + threadIdx.x;
    const int g = blockIdx.x / ctiles;
    float sum = 0.f;
    #pragma unroll
    for (int k = 0; k < 16; ++k)
        sum += partials[(size_t)(g * 16 + k) * N_OUT + c];
    partials[(size_t)(g * 16) * N_OUT + c] = sum;
}

// Kernel 2b: final reduce (rows at stride rowStride) + voltage/spike update.
__global__ __launch_bounds__(256) void lif_v_kernel(
    const float* __restrict__ voltages,
    const float* __restrict__ partials,
    float* __restrict__ out,            // [0,N)=spikes, [N,2N)=v_new
    int nGroups, int rowStride)
{
    const int c = blockIdx.x * blockDim.x + threadIdx.x;
    const float v     = voltages[c] * V_DECAY;
    const float spike = (v >= THRESH) ? 1.0f : 0.0f;
    float sum = 0.f;
    #pragma unroll 8
    for (int g = 0; g < nGroups; ++g)
        sum += partials[(size_t)(g * rowStride) * N_OUT + c];
    out[c]         = spike;
    out[N_OUT + c] = v + sum - spike * THRESH;
}

extern "C" void kernel_launch(void* const* d_in, const int* in_sizes, int n_in,
                              void* d_out, int out_size, void* d_ws, size_t ws_size,
                              hipStream_t stream) {
    const float* input_spikes = (const float*)d_in[0];
    const float* voltages     = (const float*)d_in[1];
    const float* synapses     = (const float*)d_in[2];
    const float* weights      = (const float*)d_in[3];

    float* out      = (float*)d_out;
    float* syn_out  = out + 2 * N_OUT;
    float* partials = (float*)d_ws;

    // Blocks = row chunks. 512 blocks x 16 rows preferred (16.8 MB ws, known to
    // fit from R3/R4). Shrink if ws_size is smaller.
    int chunks = 512;
    while (chunks > 1 && (size_t)chunks * N_OUT * sizeof(float) > ws_size)
        chunks >>= 1;
    const int rowsPerBlock = N_IN / chunks;

    lif_syn_kernel<<<dim3(chunks), dim3(256), 0, stream>>>(
        input_spikes, synapses, weights, syn_out, partials, rowsPerBlock);

    if (chunks >= 16) {
        lif_reduce_kernel<<<dim3((N_OUT / 256) * (chunks / 16)), dim3(256), 0,
                            stream>>>(partials);
        lif_v_kernel<<<dim3(N_OUT / 256), dim3(256), 0, stream>>>(
            voltages, partials, out, chunks / 16, 16);
    } else {
        lif_v_kernel<<<dim3(N_OUT / 256), dim3(256), 0, stream>>>(
            voltages, partials, out, chunks, 1);
    }
}

// Round 7
// 160.135 us; speedup vs baseline: 1.3000x; 1.0465x over previous
//
#include <hip/hip_runtime.h>

// LIF layer fused step, f32.
// Inputs: input_spikes[8192], voltages[1,8192], synapses[8192,8192], weights[8192,8192]
// Outputs (concat in d_out): spikes[8192] (0/1 f32), v_new[8192], syn[8192,8192]

#define V_DECAY 0.99004983374916811f   // exp(-1/100)
#define S_DECAY 0.98019867330675525f   // exp(-1/50)
#define THRESH  1.0f

constexpr int N_IN  = 8192;
constexpr int N_OUT = 8192;
constexpr int HALF  = 4096;            // columns per block (256 thr * 4 f * 4 steps)

typedef float f32x4 __attribute__((ext_vector_type(4)));

// One row-half = 8 dwordx4 loads (4 synapse + 4 weight steps, stride 4 KB).
#define DECL_SET(P) f32x4 P##s0, P##s1, P##s2, P##s3, P##w0, P##w1, P##w2, P##w3; float P##sp;

#define LOAD_SET(P, ROW) do {                                        \
    const size_t b_ = (size_t)(ROW) * N_OUT + c0;                    \
    P##s0 = *(const f32x4*)(synapses + b_);                          \
    P##s1 = *(const f32x4*)(synapses + b_ + 1024);                   \
    P##s2 = *(const f32x4*)(synapses + b_ + 2048);                   \
    P##s3 = *(const f32x4*)(synapses + b_ + 3072);                   \
    P##w0 = *(const f32x4*)(weights  + b_);                          \
    P##w1 = *(const f32x4*)(weights  + b_ + 1024);                   \
    P##w2 = *(const f32x4*)(weights  + b_ + 2048);                   \
    P##w3 = *(const f32x4*)(weights  + b_ + 3072);                   \
    P##sp = input_spikes[ROW];                                       \
} while (0)

// Regalloc cannot cheat an asm that reads all 8 results: all 8 loads must be
// issued and live here. (sched_barrier alone failed in R6: VGPR=52 < 64.)
#define PIN_SET(P)                                                   \
    asm volatile("" : "+v"(P##s0), "+v"(P##s1), "+v"(P##s2), "+v"(P##s3), \
                      "+v"(P##w0), "+v"(P##w1), "+v"(P##w2), "+v"(P##w3))

#define COMP_SET(P, ROW) do {                                        \
    const size_t b_ = (size_t)(ROW) * N_OUT + c0;                    \
    const f32x4 o0 = P##s0 * S_DECAY + P##w0 * P##sp;                \
    const f32x4 o1 = P##s1 * S_DECAY + P##w1 * P##sp;                \
    const f32x4 o2 = P##s2 * S_DECAY + P##w2 * P##sp;                \
    const f32x4 o3 = P##s3 * S_DECAY + P##w3 * P##sp;                \
    *(f32x4*)(syn_out + b_)        = o0;                             \
    *(f32x4*)(syn_out + b_ + 1024) = o1;                             \
    *(f32x4*)(syn_out + b_ + 2048) = o2;                             \
    *(f32x4*)(syn_out + b_ + 3072) = o3;                             \
    acc0 += o0; acc1 += o1; acc2 += o2; acc3 += o3;                  \
} while (0)

// Kernel 1: block = (column half h, 16-row chunk rc). Two-row software
// pipeline: while computing row set A (pinned live by asm), row set B's 8
// loads are already in flight. 1024 blocks -> 4 blocks/CU -> 16 waves/CU,
// each holding 8-16 KB in flight => ~128-256 KB/CU outstanding.
__global__ __launch_bounds__(256, 4) void lif_syn_kernel(
    const float* __restrict__ input_spikes,
    const float* __restrict__ synapses,
    const float* __restrict__ weights,
    float* __restrict__ syn_out,
    float* __restrict__ partials,       // [chunks][N_OUT]
    int rowsPerChunk)                   // multiple of 16
{
    const int h    = blockIdx.x & 1;
    const int rc   = blockIdx.x >> 1;
    const int c0   = h * HALF + threadIdx.x * 4;
    const int row0 = rc * rowsPerChunk;

    f32x4 acc0 = (f32x4)(0.f), acc1 = (f32x4)(0.f),
          acc2 = (f32x4)(0.f), acc3 = (f32x4)(0.f);

    DECL_SET(A); DECL_SET(B);

    for (int rr = 0; rr < rowsPerChunk; rr += 16) {
        const int rbase = row0 + rr;
        LOAD_SET(A, rbase);
        #pragma unroll
        for (int r = 0; r < 16; r += 2) {
            LOAD_SET(B, rbase + r + 1);
            __builtin_amdgcn_sched_barrier(0);
            PIN_SET(A);
            COMP_SET(A, rbase + r);
            if (r + 2 < 16) LOAD_SET(A, rbase + r + 2);
            __builtin_amdgcn_sched_barrier(0);
            PIN_SET(B);
            COMP_SET(B, rbase + r + 1);
        }
    }

    const size_t pbase = (size_t)rc * N_OUT + c0;
    *(f32x4*)(partials + pbase)        = acc0;
    *(f32x4*)(partials + pbase + 1024) = acc1;
    *(f32x4*)(partials + pbase + 2048) = acc2;
    *(f32x4*)(partials + pbase + 3072) = acc3;
}

// Kernel 2a: 16:1 reduction. Group g reads rows [16g, 16g+16), writes row 16g
// (its OWN first input row) — no cross-group overlap, deterministic.
__global__ __launch_bounds__(256) void lif_reduce_kernel(
    float* __restrict__ partials)
{
    const int ctiles = N_OUT / 256;                    // 32
    const int c = (blockIdx.x % ctiles) * 256 + threadIdx.x;
    const int g = blockIdx.x / ctiles;
    float sum = 0.f;
    #pragma unroll
    for (int k = 0; k < 16; ++k)
        sum += partials[(size_t)(g * 16 + k) * N_OUT + c];
    partials[(size_t)(g * 16) * N_OUT + c] = sum;
}

// Kernel 2b: final reduce (rows at stride rowStride) + voltage/spike update.
__global__ __launch_bounds__(256) void lif_v_kernel(
    const float* __restrict__ voltages,
    const float* __restrict__ partials,
    float* __restrict__ out,            // [0,N)=spikes, [N,2N)=v_new
    int nGroups, int rowStride)
{
    const int c = blockIdx.x * blockDim.x + threadIdx.x;
    const float v     = voltages[c] * V_DECAY;
    const float spike = (v >= THRESH) ? 1.0f : 0.0f;
    float sum = 0.f;
    #pragma unroll 8
    for (int g = 0; g < nGroups; ++g)
        sum += partials[(size_t)(g * rowStride) * N_OUT + c];
    out[c]         = spike;
    out[N_OUT + c] = v + sum - spike * THRESH;
}

extern "C" void kernel_launch(void* const* d_in, const int* in_sizes, int n_in,
                              void* d_out, int out_size, void* d_ws, size_t ws_size,
                              hipStream_t stream) {
    const float* input_spikes = (const float*)d_in[0];
    const float* voltages     = (const float*)d_in[1];
    const float* synapses     = (const float*)d_in[2];
    const float* weights      = (const float*)d_in[3];

    float* out      = (float*)d_out;
    float* syn_out  = out + 2 * N_OUT;
    float* partials = (float*)d_ws;

    // 512 chunks x 16 rows (16.8 MB ws — fits, proven R4/R6). Fallback halves
    // chunks; rowsPerChunk stays a multiple of 16.
    int chunks = 512;
    while (chunks > 1 && (size_t)chunks * N_OUT * sizeof(float) > ws_size)
        chunks >>= 1;
    const int rowsPerChunk = N_IN / chunks;

    lif_syn_kernel<<<dim3(2 * chunks), dim3(256), 0, stream>>>(
        input_spikes, synapses, weights, syn_out, partials, rowsPerChunk);

    if (chunks >= 16) {
        lif_reduce_kernel<<<dim3((N_OUT / 256) * (chunks / 16)), dim3(256), 0,
                            stream>>>(partials);
        lif_v_kernel<<<dim3(N_OUT / 256), dim3(256), 0, stream>>>(
            voltages, partials, out, chunks / 16, 16);
    } else {
        lif_v_kernel<<<dim3(N_OUT / 256), dim3(256), 0, stream>>>(
            voltages, partials, out, chunks, 1);
    }
}